// Round 8
// baseline (696.704 us; speedup 1.0000x reference)
//
#include <hip/hip_runtime.h>
#include <hip/hip_bf16.h>
#include <stdint.h>

typedef __attribute__((ext_vector_type(4))) int i32x4;

#define M_DIM 8192
#define K_DIM 4096
#define N_DIM 16384
#define NELEM_W ((long)N_DIM * (long)K_DIM) /* 67108864 */
#define NELEM_X ((long)M_DIM * (long)K_DIM) /* 33554432 */

// ---------------- helpers ----------------

__device__ __forceinline__ void g2l16(const void* g, void* l) {
  __builtin_amdgcn_global_load_lds(
      (const __attribute__((address_space(1))) unsigned int*)g,
      (__attribute__((address_space(3))) unsigned int*)l, 16, 0, 0);
}

// ---------------- scale = max(mean(|W|), 1e-8), deterministic fp64 ----------------

__global__ void reduce_absw(const float4* __restrict__ w4, double* __restrict__ partials, int n4) {
  const int tid = threadIdx.x;
  double s = 0.0;
  const int stride = gridDim.x * blockDim.x;
  for (int i = blockIdx.x * blockDim.x + tid; i < n4; i += stride) {
    float4 v = w4[i];
    s += (double)fabsf(v.x);
    s += (double)fabsf(v.y);
    s += (double)fabsf(v.z);
    s += (double)fabsf(v.w);
  }
  __shared__ double sd[256];
  sd[tid] = s;
  __syncthreads();
  for (int off = 128; off > 0; off >>= 1) {
    if (tid < off) sd[tid] += sd[tid + off];
    __syncthreads();
  }
  if (tid == 0) partials[blockIdx.x] = sd[0];
}

__global__ void finalize_scale(const double* __restrict__ partials, float* __restrict__ sp) {
  const int tid = threadIdx.x;
  double s = 0.0;
#pragma unroll
  for (int j = 0; j < 8; ++j) s += partials[tid * 8 + j];
  __shared__ double sd[256];
  sd[tid] = s;
  __syncthreads();
  for (int off = 128; off > 0; off >>= 1) {
    if (tid < off) sd[tid] += sd[tid + off];
    __syncthreads();
  }
  if (tid == 0) {
    double mean = sd[0] / (double)NELEM_W;
    float sc = (float)mean;
    if (sc < 1e-8f) sc = 1e-8f;
    sp[0] = sc;
  }
}

// ---------------- quantize W -> ternary int8 {-1,0,+1} ----------------

__global__ void quant_w_i8(const float4* __restrict__ w4, char* __restrict__ q,
                           const float* __restrict__ sp, int n4) {
  const float sc = sp[0];
  const int stride = gridDim.x * blockDim.x;
  for (int i = blockIdx.x * blockDim.x + threadIdx.x; i < n4; i += stride) {
    float4 v = w4[i];
    char4 o;
    o.x = (char)rintf(fminf(fmaxf(v.x / sc, -1.f), 1.f));
    o.y = (char)rintf(fminf(fmaxf(v.y / sc, -1.f), 1.f));
    o.z = (char)rintf(fminf(fmaxf(v.z / sc, -1.f), 1.f));
    o.w = (char)rintf(fminf(fmaxf(v.w / sc, -1.f), 1.f));
    *(char4*)(q + (long)i * 4) = o;
  }
}

// ---------------- quantize x rows -> int8 with per-row scale ----------------

__global__ __launch_bounds__(256)
void quant_x_i8(const float* __restrict__ x, char* __restrict__ xq,
                float* __restrict__ s_row) {
  const int row = blockIdx.x;
  const int tid = threadIdx.x;
  const float4* xr = (const float4*)(x + (long)row * K_DIM);
  float4 v[4];
  float m = 0.f;
#pragma unroll
  for (int k = 0; k < 4; ++k) {
    v[k] = xr[tid + 256 * k];
    m = fmaxf(m, fmaxf(fmaxf(fabsf(v[k].x), fabsf(v[k].y)),
                       fmaxf(fabsf(v[k].z), fabsf(v[k].w))));
  }
  __shared__ float red[256];
  red[tid] = m;
  __syncthreads();
  for (int off = 128; off > 0; off >>= 1) {
    if (tid < off) red[tid] = fmaxf(red[tid], red[tid + off]);
    __syncthreads();
  }
  const float mx = red[0];
  const float inv = (mx > 0.f) ? (127.f / mx) : 0.f;
  if (tid == 0) s_row[row] = (mx > 0.f) ? (mx / 127.f) : 0.f;
  char4* out = (char4*)(xq + (long)row * K_DIM);
#pragma unroll
  for (int k = 0; k < 4; ++k) {
    char4 o;
    o.x = (char)fminf(fmaxf(rintf(v[k].x * inv), -127.f), 127.f);
    o.y = (char)fminf(fmaxf(rintf(v[k].y * inv), -127.f), 127.f);
    o.z = (char)fminf(fmaxf(rintf(v[k].z * inv), -127.f), 127.f);
    o.w = (char)fminf(fmaxf(rintf(v[k].w * inv), -127.f), 127.f);
    out[tid + 256 * k] = o;
  }
}

// ---------------- 256x256 i8 GEMM, 16x16x64 MFMA, ONE barrier per K-tile ----------------
// r7 datapath (LDS layout, swizzle, staging addressing, epilogue unchanged).
// NEW sync structure: staging is t+1-ONLY into buf^1 (never the buffer being read)
// => no intra-tile barriers needed. Per K-tile group:
//   { issue 8 stage loads (t+1 -> buf^1); 24 ds_reads + 64 MFMA interleaved
//     (8 sub-phases of 8 MFMA, JIT prefetch reads between blocks); vmcnt(0)
//     (drains own stage loads, aged ~full group >> HBM latency); s_barrier }.
// The group-end barrier is the universal ordering point:
//   - stage into buf^1 legal: its readers (tile t-1) passed that barrier;
//   - reads of buf_t legal: t's loads drained (each wave vmcnt(0)) + joined;
//   - all reads are consumed by in-group MFMAs (operand waits) before the barrier.
// Waves slip freely inside the group -> LDS-read windows hide under other waves'
// (and own, via sub-phase prefetch) MFMA windows. 32 barriers total (was 128).

template<int MP, int NP, int AH>
__device__ __forceinline__ void mb(i32x4 (&acc)[8][4], const i32x4 (&a)[8], const i32x4 (&b)[8]) {
#pragma unroll
  for (int dm = 0; dm < 2; ++dm)
#pragma unroll
    for (int dn = 0; dn < 2; ++dn)
#pragma unroll
      for (int ks = 0; ks < 2; ++ks)
        acc[MP * 2 + dm][NP * 2 + dn] = __builtin_amdgcn_mfma_i32_16x16x64_i8(
            a[AH + dm * 2 + ks], b[NP * 4 + dn * 2 + ks], acc[MP * 2 + dm][NP * 2 + dn], 0, 0, 0);
}

#define FENCE asm volatile("" ::: "memory")
#define BAR do { FENCE; __builtin_amdgcn_s_barrier(); FENCE; } while (0)
#define VMW0 asm volatile("s_waitcnt vmcnt(0)" ::: "memory")
#define PRIO1 __builtin_amdgcn_s_setprio(1)
#define PRIO0 __builtin_amdgcn_s_setprio(0)

#define STG_A(bb, h, kt) do { \
    const char* g_ = Ac + aG + (unsigned)(h) * 524288u + (unsigned)(kt) * 128u; \
    char* l_ = lds + (unsigned)(bb) * 32768u + (unsigned)(h) * 16384u + ldsT; \
    g2l16(g_, l_); g2l16(g_ + 262144u, l_ + 8192u); \
  } while (0)
#define STG_B(bb, h, kt) do { \
    const char* g_ = Bc + bG + (unsigned)(h) * 524288u + (unsigned)(kt) * 128u; \
    char* l_ = lds + 65536u + (unsigned)(bb) * 32768u + (unsigned)(h) * 16384u + ldsT; \
    g2l16(g_, l_); g2l16(g_ + 262144u, l_ + 8192u); \
  } while (0)

#define LDA_(d, bb, m, ks) d = *(const i32x4*)(lds + Abase##bb + (unsigned)(m) * 2048u + frk + coff##ks)
#define LDB_(d, bb, n, ks) d = *(const i32x4*)(lds + Bbase##bb + (unsigned)(n) * 2048u + frk + coff##ks)

// read A m-pair mp into a[AH..AH+3]; read B n-pair np into b[4np..4np+3]
#define RD_A(AH, bb, mp) do { \
    LDA_(a[(AH) + 0], bb, 2 * (mp) + 0, 0); LDA_(a[(AH) + 1], bb, 2 * (mp) + 0, 1); \
    LDA_(a[(AH) + 2], bb, 2 * (mp) + 1, 0); LDA_(a[(AH) + 3], bb, 2 * (mp) + 1, 1); \
  } while (0)
#define RD_B(bb, np) do { \
    LDB_(b[4 * (np) + 0], bb, 2 * (np) + 0, 0); LDB_(b[4 * (np) + 1], bb, 2 * (np) + 0, 1); \
    LDB_(b[4 * (np) + 2], bb, 2 * (np) + 1, 0); LDB_(b[4 * (np) + 3], bb, 2 * (np) + 1, 1); \
  } while (0)

// one K-tile group: read buf bb, stage kt1 -> buf obb (if DO_STG)
// sub-phase snake order (m01,n01)(m01,n23)(m23,n23)(m23,n01)(m45,n01)(m45,n23)(m67,n23)(m67,n01)
#define TILE(bb, obb, kt1, DO_STG) do { \
    if (DO_STG) { STG_A(obb, 0, kt1); STG_A(obb, 1, kt1); STG_B(obb, 0, kt1); STG_B(obb, 1, kt1); } \
    RD_A(0, bb, 0); RD_B(bb, 0); \
    PRIO1; mb<0, 0, 0>(acc, a, b); PRIO0; \
    RD_A(4, bb, 1); RD_B(bb, 1); \
    PRIO1; mb<0, 1, 0>(acc, a, b); PRIO0; \
    RD_A(0, bb, 2); \
    PRIO1; mb<1, 1, 4>(acc, a, b); PRIO0; \
    PRIO1; mb<1, 0, 4>(acc, a, b); PRIO0; \
    RD_A(4, bb, 3); \
    PRIO1; mb<2, 0, 0>(acc, a, b); PRIO0; \
    PRIO1; mb<2, 1, 0>(acc, a, b); PRIO0; \
    PRIO1; mb<3, 1, 4>(acc, a, b); PRIO0; \
    PRIO1; mb<3, 0, 4>(acc, a, b); PRIO0; \
  } while (0)

__global__ __launch_bounds__(512, 2)
void gemm_i8(const char* __restrict__ A, const char* __restrict__ B,
             float* __restrict__ C, const float* __restrict__ sp,
             const float* __restrict__ s_row) {
  extern __shared__ char lds[];

  const int tid = threadIdx.x;
  const int wave = tid >> 6, lane = tid & 63;
  const int fr = lane & 15, fq = lane >> 4;
  const int wr = wave >> 2;        // 0..1 (M)
  const int wc = wave & 3;         // 0..3 (N)

  // bijective XCD swizzle (2048 % 8 == 0)
  int wgid = blockIdx.x;
  wgid = (wgid & 7) * ((int)gridDim.x >> 3) + (wgid >> 3);
  const int bm = wgid >> 6;
  const int bn = wgid & 63;

  // staging addressing (identical to r5/r7)
  const int r0 = tid >> 3;
  const int pslot = tid & 7;
  const int lslot = pslot ^ (r0 & 7);
  const unsigned aG = (unsigned)(bm * 256 + r0) * (unsigned)K_DIM + (unsigned)lslot * 16u;
  const unsigned bG = (unsigned)(bn * 256 + r0) * (unsigned)K_DIM + (unsigned)lslot * 16u;
  const unsigned ldsT = (unsigned)tid * 16u;
  const char* Ac = A;
  const char* Bc = B;

  // fragment read addressing (identical): rows 128B, phys slot = logical ^ (row&7)
  const unsigned axor = (unsigned)(fr & 7) << 4;
  const unsigned coff0 = ((unsigned)(fq * 16)) ^ axor;
  const unsigned coff1 = ((unsigned)(64 + fq * 16)) ^ axor;
  const unsigned frk = (unsigned)fr * 128u;
  const unsigned Abase0 = (unsigned)(wr * 16384);
  const unsigned Abase1 = (unsigned)(32768 + wr * 16384);
  const unsigned Bhalf = (unsigned)(65536 + (wc >> 1) * 16384 + (wc & 1) * 8192);
  const unsigned Bbase0 = Bhalf;
  const unsigned Bbase1 = Bhalf + 32768u;

  i32x4 acc[8][4] = {};
  i32x4 a[8], b[8];

  // prologue: stage t0 -> buf0 (8 loads); hard drain (one-time); join
  STG_A(0, 0, 0); STG_A(0, 1, 0); STG_B(0, 0, 0); STG_B(0, 1, 0);
  VMW0;
  BAR;

#pragma unroll 1
  for (int i = 0; i < 15; ++i) {
    TILE(0, 1, 2 * i + 1, true);   // t=2i   reads buf0, stages t+1 -> buf1
    VMW0; BAR;
    TILE(1, 0, 2 * i + 2, true);   // t=2i+1 reads buf1, stages t+2 -> buf0
    VMW0; BAR;
  }
  TILE(0, 1, 31, true);            // t=30: stage t31 -> buf1
  VMW0; BAR;
  TILE(1, 0, 0, false);            // t=31: compute only

  // epilogue: C/D layout col = lane&15 (fr), row = fq*4 + j; out = acc * s_row[row] * sw
  const float sw = sp[0];
  const int crow0 = bm * 256 + wr * 128 + fq * 4;
  const int ccol0 = bn * 256 + wc * 64 + fr;
#pragma unroll
  for (int m = 0; m < 8; ++m) {
#pragma unroll
    for (int j = 0; j < 4; ++j) {
      const int row = crow0 + m * 16 + j;
      const float sc = s_row[row] * sw;
#pragma unroll
      for (int n = 0; n < 4; ++n) {
        C[(long)row * N_DIM + (ccol0 + n * 16)] = (float)acc[m][n][j] * sc;
      }
    }
  }
}

// ---------------- fallback (ws too small): bf16 on-the-fly 128^2 ----------------

typedef __hip_bfloat16 bf16;
typedef __attribute__((ext_vector_type(8))) short short8;
typedef __attribute__((ext_vector_type(4))) float f32x4;

__device__ __forceinline__ unsigned short f2bf(float f) {
  unsigned int u = __float_as_uint(f);
  u += 0x7FFFu + ((u >> 16) & 1u);
  return (unsigned short)(u >> 16);
}

__global__ __launch_bounds__(256)
void gemm_fly(const float* __restrict__ X, const float* __restrict__ W,
              float* __restrict__ C, const float* __restrict__ sp) {
  __shared__ alignas(16) bf16 As[128 * 32];
  __shared__ alignas(16) bf16 Bs[128 * 32];

  const int tid = threadIdx.x;
  const int wave = tid >> 6;
  const int lane = tid & 63;

  int wgid = blockIdx.x;
  wgid = (wgid & 7) * ((int)gridDim.x >> 3) + (wgid >> 3);
  const int nbn = N_DIM / 128;
  const int bm = wgid / nbn;
  const int bn = wgid % nbn;

  const float sc = sp[0];

  const int wr = (wave >> 1) * 64;
  const int wc = (wave & 1) * 64;
  const int fr = lane & 15;
  const int fq = lane >> 4;
  const char* AsB = (const char*)As;
  const char* BsB = (const char*)Bs;
  const unsigned aoff = (unsigned)((wr + fr) * 64 + fq * 16);
  const unsigned boff = (unsigned)((wc + fr) * 64 + fq * 16);

  f32x4 acc[4][4] = {};

  for (int kt = 0; kt < K_DIM; kt += 32) {
#pragma unroll
    for (int r = 0; r < 4; ++r) {
      int e = r * 1024 + tid * 4;
      int row = e >> 5;
      int k4 = e & 31;
      float4 xv = *(const float4*)(X + (long)(bm * 128 + row) * K_DIM + kt + k4);
      ushort4 xb;
      xb.x = f2bf(xv.x); xb.y = f2bf(xv.y); xb.z = f2bf(xv.z); xb.w = f2bf(xv.w);
      *(ushort4*)(As + e) = xb;
      float4 wv = *(const float4*)(W + (long)(bn * 128 + row) * K_DIM + kt + k4);
      ushort4 wb;
      wb.x = f2bf(rintf(fminf(fmaxf(wv.x / sc, -1.f), 1.f)));
      wb.y = f2bf(rintf(fminf(fmaxf(wv.y / sc, -1.f), 1.f)));
      wb.z = f2bf(rintf(fminf(fmaxf(wv.z / sc, -1.f), 1.f)));
      wb.w = f2bf(rintf(fminf(fmaxf(wv.w / sc, -1.f), 1.f)));
      *(ushort4*)(Bs + e) = wb;
    }
    __syncthreads();

    short8 a[4], b[4];
#pragma unroll
    for (int m = 0; m < 4; ++m)
      a[m] = *(const short8*)(AsB + aoff + m * (16 * 64));
#pragma unroll
    for (int n = 0; n < 4; ++n)
      b[n] = *(const short8*)(BsB + boff + n * (16 * 64));
#pragma unroll
    for (int m = 0; m < 4; ++m)
#pragma unroll
      for (int n = 0; n < 4; ++n)
        acc[m][n] = __builtin_amdgcn_mfma_f32_16x16x32_bf16(a[m], b[n], acc[m][n], 0, 0, 0);

    __syncthreads();
  }

  const long crow0 = (long)(bm * 128 + wr + fq * 4);
  const int ccol0 = bn * 128 + wc + fr;
#pragma unroll
  for (int m = 0; m < 4; ++m)
#pragma unroll
    for (int n = 0; n < 4; ++n)
#pragma unroll
      for (int j = 0; j < 4; ++j) {
        long row = crow0 + (long)(m * 16 + j);
        int col = ccol0 + n * 16;
        C[row * N_DIM + col] = acc[m][n][j] * sc;
      }
}

// ---------------- launch ----------------

extern "C" void kernel_launch(void* const* d_in, const int* in_sizes, int n_in,
                              void* d_out, int out_size, void* d_ws, size_t ws_size,
                              hipStream_t stream) {
  const float* x = (const float*)d_in[0];
  const float* w = (const float*)d_in[1];
  float* out = (float*)d_out;

  char* ws = (char*)d_ws;
  double* partials = (double*)ws;                 // 16 KB
  float* sp = (float*)(ws + 16384);               // scale (mean|W|)
  const size_t SROW_OFF = 32768;                  // 8192 floats = 32 KB
  const size_t WQ_OFF = SROW_OFF + 32768;
  const size_t XQ_OFF = WQ_OFF + (size_t)NELEM_W; // i8
  const size_t NEEDED = XQ_OFF + (size_t)NELEM_X; // ~96 MB

  reduce_absw<<<2048, 256, 0, stream>>>((const float4*)w, partials, (int)(NELEM_W / 4));
  finalize_scale<<<1, 256, 0, stream>>>(partials, sp);

  if (ws_size >= NEEDED) {
    float* s_row = (float*)(ws + SROW_OFF);
    char* wq = ws + WQ_OFF;
    char* xq = ws + XQ_OFF;
    quant_w_i8<<<2048, 256, 0, stream>>>((const float4*)w, wq, sp, (int)(NELEM_W / 4));
    quant_x_i8<<<M_DIM, 256, 0, stream>>>(x, xq, s_row);

    static const int lds_bytes = 131072;
    (void)hipFuncSetAttribute((const void*)gemm_i8,
                              hipFuncAttributeMaxDynamicSharedMemorySize, lds_bytes);
    const int grid = (M_DIM / 256) * (N_DIM / 256); // 2048
    gemm_i8<<<grid, 512, lds_bytes, stream>>>(xq, wq, out, sp, s_row);
  } else {
    const int grid = (M_DIM / 128) * (N_DIM / 128);
    gemm_fly<<<grid, 256, 0, stream>>>(x, w, out, sp);
  }
}